// Round 4
// baseline (168.834 us; speedup 1.0000x reference)
//
#include <hip/hip_runtime.h>
#include <cstdint>

#define PERB 262144   // C*H*H = N*D elements per batch

typedef __attribute__((ext_vector_type(8))) short bf16x8;
typedef __attribute__((ext_vector_type(4))) float f32x4;
typedef unsigned short ushort_t;

__device__ __forceinline__ uint16_t f2bf(float f) {
    uint32_t u = __float_as_uint(f);
    u += 0x7fff + ((u >> 16) & 1);   // RNE
    return (uint16_t)(u >> 16);
}

// async global->LDS, 16B per lane. LDS dest is wave-uniform base (+lane*16 by HW);
// global src is per-lane.
__device__ __forceinline__ void glds16(const void* g, void* l) {
    __builtin_amdgcn_global_load_lds(
        (const __attribute__((address_space(1))) void*)g,
        (__attribute__((address_space(3))) void*)l, 16, 0, 0);
}

// ---------------------------------------------------------------------------
// Kernel 0: fused prep.
//   blocks [0,256)   : convert the 4 weight matrices (256x256 fp32) to bf16
//   blocks [256,768) : LayerNorm over channel axis -> bf16 X
// ---------------------------------------------------------------------------
__global__ __launch_bounds__(256) void prep_kernel(
    const float* __restrict__ x, const float* __restrict__ gam,
    const float* __restrict__ bet, ushort_t* __restrict__ X,
    const float* __restrict__ wq, const float* __restrict__ wk,
    const float* __restrict__ wv, const float* __restrict__ wo,
    ushort_t* __restrict__ oq, ushort_t* __restrict__ ok,
    ushort_t* __restrict__ ov, ushort_t* __restrict__ oo)
{
    const int blk = blockIdx.x;
    const int tid = threadIdx.x;
    if (blk < 256) {
        const int which = blk >> 6;
        const int idx = ((blk & 63) * 256 + tid) * 4;
        const float* src = which == 0 ? wq : which == 1 ? wk : which == 2 ? wv : wo;
        ushort_t* dst    = which == 0 ? oq : which == 1 ? ok : which == 2 ? ov : oo;
        const float4 v = *(const float4*)&src[idx];
        uint2 p;
        p.x = (uint32_t)f2bf(v.x) | ((uint32_t)f2bf(v.y) << 16);
        p.y = (uint32_t)f2bf(v.z) | ((uint32_t)f2bf(v.w) << 16);
        *(uint2*)&dst[idx] = p;
        return;
    }
    const int lb  = blk - 256;            // 512 blocks
    const int b   = lb >> 5;
    const int sp0 = (lb & 31) << 5;
    const int spl = tid & 31;
    const int cg  = tid >> 5;
    const int c0  = cg << 5;
    const int sp  = sp0 + spl;
    const float* xb = x + (size_t)b * PERB + sp;

    float vals[32];
    float s = 0.f, sq = 0.f;
#pragma unroll
    for (int i = 0; i < 32; ++i) {
        float v = xb[(size_t)(c0 + i) * 1024];
        vals[i] = v; s += v; sq += v * v;
    }
    __shared__ float rs[8][32];
    __shared__ float rq[8][32];
    rs[cg][spl] = s; rq[cg][spl] = sq;
    __syncthreads();
    float ts = 0.f, tq = 0.f;
#pragma unroll
    for (int g = 0; g < 8; ++g) { ts += rs[g][spl]; tq += rq[g][spl]; }
    const float mean = ts * (1.f / 256.f);
    const float var  = tq * (1.f / 256.f) - mean * mean;
    const float rstd = rsqrtf(var + 1e-5f);

    ushort_t* Xb = X + (size_t)b * PERB + sp;
#pragma unroll
    for (int i = 0; i < 32; ++i) {
        const int cc = c0 + i;
        Xb[(size_t)cc * 1024] = f2bf((vals[i] - mean) * rstd * gam[cc] + bet[cc]);
    }
}

// ---------------------------------------------------------------------------
// Kernel 2: MFMA fused Q/K/V projection (glds staging, round-3 structure).
//  Round-4 change: epilogue writes Q,K TOKEN-MAJOR [b][h][tok][s] via clean
//  uint2 stores (same store count as before, different address) so attn can
//  stage K with one global_load_lds per chunk and Q with bf16x8 loads.
//  V stays feature-major (attn PV wants it that way).
// ---------------------------------------------------------------------------
__device__ __forceinline__ void qkv_stage(
    ushort_t* Sb, const ushort_t* __restrict__ X,
    const ushort_t* __restrict__ wq, const ushort_t* __restrict__ wk,
    const ushort_t* __restrict__ wv,
    int m0, int n0, int k0, int w, int lane)
{
    const int rsub = lane >> 3;          // 0..7  row-within-8-group
    const int u    = lane & 7;           // 16B unit within 128B row
    const int koct = u ^ rsub;           // pre-swizzled global k-octet
#pragma unroll
    for (int i = 0; i < 2; ++i) {
        const int rg  = w * 2 + i;       // 8-row group 0..7
        const int row = rg * 8 + rsub;   // row&7 == rsub
        const int go  = k0 + koct * 8;
        ushort_t* db = Sb + rg * 512;    // wave-uniform dest base (+lane*16B by HW)
        glds16(&X [(size_t)(m0 + row) * 256 + go], db);
        glds16(&wq[(size_t)(n0 + row) * 256 + go], db + 4096);
        glds16(&wk[(size_t)(n0 + row) * 256 + go], db + 8192);
        glds16(&wv[(size_t)(n0 + row) * 256 + go], db + 12288);
    }
}

__device__ __forceinline__ void qkv_compute(
    const ushort_t* Sb, int w, int c, int quad, f32x4 acc[3][4])
{
#pragma unroll
    for (int ks = 0; ks < 2; ++ks) {
        const int kq = ks * 4 + quad;
        const int uo = (kq ^ (c & 7)) * 8;
        bf16x8 af[4];
#pragma unroll
        for (int msub = 0; msub < 4; ++msub)
            af[msub] = *(const bf16x8*)&Sb[(msub * 16 + c) * 64 + uo];
        bf16x8 bw[3];
#pragma unroll
        for (int o3 = 0; o3 < 3; ++o3)
            bw[o3] = *(const bf16x8*)&Sb[(o3 + 1) * 4096 + (w * 16 + c) * 64 + uo];
#pragma unroll
        for (int o3 = 0; o3 < 3; ++o3)
#pragma unroll
            for (int msub = 0; msub < 4; ++msub)
                acc[o3][msub] = __builtin_amdgcn_mfma_f32_16x16x32_bf16(
                    bw[o3], af[msub], acc[o3][msub], 0, 0, 0);
    }
}

__global__ __launch_bounds__(256) void qkv_kernel(
    const ushort_t* __restrict__ X,
    const ushort_t* __restrict__ wq, const float* __restrict__ bq,
    const ushort_t* __restrict__ wk, const float* __restrict__ bk,
    const ushort_t* __restrict__ wv, const float* __restrict__ bv,
    ushort_t* __restrict__ QT, ushort_t* __restrict__ KT, ushort_t* __restrict__ V)
{
    __shared__ __align__(16) ushort_t SB0[4][4096];
    __shared__ __align__(16) ushort_t SB1[4][4096];

    const int blk = blockIdx.x;
    const int m0  = (blk >> 2) << 6;
    const int n0  = (blk & 3) << 6;
    const int tid = threadIdx.x;
    const int w    = tid >> 6;
    const int lane = tid & 63;
    const int quad = lane >> 4;
    const int c    = lane & 15;

    f32x4 acc[3][4];
#pragma unroll
    for (int o3 = 0; o3 < 3; ++o3)
#pragma unroll
        for (int i = 0; i < 4; ++i) acc[o3][i] = (f32x4){0.f, 0.f, 0.f, 0.f};

    qkv_stage(&SB0[0][0], X, wq, wk, wv, m0, n0, 0, w, lane);
    __syncthreads();
#pragma unroll
    for (int kc = 0; kc < 4; ++kc) {
        if (kc < 3) {
            if ((kc & 1) == 0)
                qkv_stage(&SB1[0][0], X, wq, wk, wv, m0, n0, (kc + 1) << 6, w, lane);
            else
                qkv_stage(&SB0[0][0], X, wq, wk, wv, m0, n0, (kc + 1) << 6, w, lane);
        }
        if ((kc & 1) == 0) qkv_compute(&SB0[0][0], w, c, quad, acc);
        else               qkv_compute(&SB1[0][0], w, c, quad, acc);
        __syncthreads();
    }

    const int n = n0 + w * 16 + quad * 4;
    const float4 bq4 = *(const float4*)&bq[n];
    const float4 bk4 = *(const float4*)&bk[n];
    const float4 bv4 = *(const float4*)&bv[n];
    const int h_ = n >> 5;               // head of this feature quad
    const int s_ = n & 31;               // s within head (4-aligned)
#pragma unroll
    for (int msub = 0; msub < 4; ++msub) {
        const int m = m0 + msub * 16 + c;      // global token row 0..16383
        // --- V: feature-major (unchanged) ---
        const f32x4 av = acc[2][msub];
        uint2 pv;
        pv.x = (uint32_t)f2bf(av[0] + bv4.x) | ((uint32_t)f2bf(av[1] + bv4.y) << 16);
        pv.y = (uint32_t)f2bf(av[2] + bv4.z) | ((uint32_t)f2bf(av[3] + bv4.w) << 16);
        *(uint2*)&V[(size_t)m * 256 + n] = pv;
        // --- Q/K: token-major [b][h][tok][s], one uint2 each ---
        const size_t tb = (size_t)(m >> 10) * PERB + (size_t)h_ * 32768
                        + (size_t)(m & 1023) * 32 + s_;
        const f32x4 aq = acc[0][msub];
        uint2 pq;
        pq.x = (uint32_t)f2bf(aq[0] + bq4.x) | ((uint32_t)f2bf(aq[1] + bq4.y) << 16);
        pq.y = (uint32_t)f2bf(aq[2] + bq4.z) | ((uint32_t)f2bf(aq[3] + bq4.w) << 16);
        *(uint2*)&QT[tb] = pq;
        const f32x4 ak = acc[1][msub];
        uint2 pk;
        pk.x = (uint32_t)f2bf(ak[0] + bk4.x) | ((uint32_t)f2bf(ak[1] + bk4.y) << 16);
        pk.y = (uint32_t)f2bf(ak[2] + bk4.z) | ((uint32_t)f2bf(ak[3] + bk4.w) << 16);
        *(uint2*)&KT[tb] = pk;
    }
}

// ---------------------------------------------------------------------------
// Kernel 3: MFMA flash attention, round-11.
//  attn stuck at 47us across all structural knobs; accounting shows ~8800
//  VALU instr/thread (~550/chunk), 3x the algorithmic need — staging machinery.
//  Fixes: K stage = 1 glds16/thread/chunk from token-major KT (was 8 scalar
//  VMEM + packs); V stage = 1 glds16 w/ pre-swizzled src (same final layout);
//  both K,V double-buffered, glds(ch+1) issued right after barrier A(ch) so
//  L2 latency hides under S+exp; wrap-free pointer induction (ch<15 guard);
//  Q staged with 2 bf16x8 loads; setprio around MFMA clusters.
// ---------------------------------------------------------------------------
#define C1F 0.09016844005556022f   // 0.0625 * log2(e)
#define LOG2EF 1.4426950408889634f

__global__ __launch_bounds__(256, 4) void attn_kernel(
    const ushort_t* __restrict__ QT, const ushort_t* __restrict__ KT,
    const ushort_t* __restrict__ V, const float* __restrict__ relb,
    ushort_t* __restrict__ O)
{
    // LDS map (bytes):
    //   [0, 16384)       P: 128 rows x 128B, 16B-unit swizzle; Q staging at start
    //   [16384, 24576)   K dbuf: buf*4096 + sg*1024 + n*16   (linear glds dest)
    //   [24576, 32768)   V dbuf: buf*4096 + d*128 + u*16     (src pre-swizzled ^d&7)
    __shared__ __align__(16) unsigned char smem[32768];
    char* Pb = (char*)smem;
    char* Kl = (char*)(smem + 16384);
    char* Vl = (char*)(smem + 24576);

    const int blk = blockIdx.x;
    const int bh  = blk & 127;
    const int mt  = blk >> 7;
    const int b   = bh >> 3;
    const int h   = bh & 7;
    const int m0  = mt << 7;
    const int tid = threadIdx.x;
    const int w    = tid >> 6;
    const int lane = tid & 63;
    const int quad = lane >> 4;
    const int c    = lane & 15;

    const size_t base = (size_t)b * PERB + (size_t)h * 32768;
    const ushort_t* QTg = QT + base;
    const ushort_t* KTg = KT + base;
    const ushort_t* Vg  = V + base;
    const float* rbh = relb + h * 3969;

    // ---- prologue: issue glds for chunk 0 (buf 0) ----
    // K: wave w stages s-group w; lane = token within chunk. LDS [sg][n][8s].
    const ushort_t* kSrc = &KTg[(size_t)lane * 32 + w * 8];
    // V: thread -> d-row tid>>3, unit tid&7, src unit pre-swizzled by ^(d&7).
    const int vd = tid >> 3, vu = tid & 7;
    const ushort_t* vSrc = &Vg[(size_t)vd * 1024 + ((vu ^ (vd & 7)) << 3)];
    char* kDst = Kl + w * 1024;      // wave-uniform base (+lane*16 by HW)
    char* vDst = Vl + w * 1024;
    glds16(kSrc, kDst);
    glds16(vSrc, vDst);
    kSrc += 2048;  vSrc += 64;

    // ---- stage Q [128m x 32s] from token-major QT ----
    {
        const int mm = tid & 127;
        const int sg2 = tid >> 7;    // 0..1, two s-octets each
        const bf16x8 q0 = *(const bf16x8*)&QTg[(size_t)(m0 + mm) * 32 + sg2 * 16];
        const bf16x8 q1 = *(const bf16x8*)&QTg[(size_t)(m0 + mm) * 32 + sg2 * 16 + 8];
        *(bf16x8*)(Pb + (sg2 * 2 + 0) * 2048 + mm * 16) = q0;
        *(bf16x8*)(Pb + (sg2 * 2 + 1) * 2048 + mm * 16) = q1;
    }
    __syncthreads();   // Q visible (also drains prologue glds)
    bf16x8 qfrag[8];
#pragma unroll
    for (int msub = 0; msub < 8; ++msub)
        qfrag[msub] = *(const bf16x8*)(Pb + quad * 2048 + (msub * 16 + c) * 16);

    // per-msub bias m-offset: idx = noff(n) + moff(m)
    int moff[8];
#pragma unroll
    for (int msub = 0; msub < 8; ++msub) {
        const int m = m0 + msub * 16 + c;
        moff[msub] = 1984 - (m >> 5) * 63 - (m & 31);
    }

    f32x4 oacc[2][2], dacc[2];
#pragma unroll
    for (int i = 0; i < 2; ++i) {
        dacc[i] = (f32x4){0.f, 0.f, 0.f, 0.f};
#pragma unroll
        for (int j = 0; j < 2; ++j) oacc[i][j] = (f32x4){0.f, 0.f, 0.f, 0.f};
    }
    bf16x8 onesf;
#pragma unroll
    for (int j = 0; j < 8; ++j) onesf[j] = (short)0x3F80;

    const int kRd = quad * 1024 + (w * 16 + c) * 16;
    const int pWr = c * 128 + (((2 * w + (quad >> 1)) ^ (c & 7)) << 4) + ((quad & 1) << 3);
    const int c7  = c & 7;

    for (int ch = 0; ch < 16; ++ch) {
        const int cb = ch & 1;
        __syncthreads();   // glds(ch) drained; PV(ch-1) done; Pb free for P-write

        // ---- issue glds for next chunk (overlaps S + exp phases) ----
        if (ch < 15) {
            const int nb = (cb ^ 1) << 12;
            glds16(kSrc, kDst + nb);
            glds16(vSrc, vDst + nb);
            kSrc += 2048;  vSrc += 64;
        }

        // ---- S phase ----
        const bf16x8 kf = *(const bf16x8*)(Kl + (cb << 12) + kRd);
        f32x4 sacc[8];
        __builtin_amdgcn_s_setprio(1);
#pragma unroll
        for (int msub = 0; msub < 8; ++msub) {
            const f32x4 z = {0.f, 0.f, 0.f, 0.f};
            sacc[msub] = __builtin_amdgcn_mfma_f32_16x16x32_bf16(kf, qfrag[msub], z, 0, 0, 0);
        }
        __builtin_amdgcn_s_setprio(0);

        // ---- bias (L1/L2-hit) + exp2 + trunc-pack + P write ----
        const int nbase = (ch << 6) + w * 16 + quad * 4;
        const int nidx0 = (nbase >> 5) * 63 + (nbase & 31);
#pragma unroll
        for (int msub = 0; msub < 8; ++msub) {
            const float* bp = rbh + nidx0 + moff[msub];
            float p[4];
#pragma unroll
            for (int r = 0; r < 4; ++r)
                p[r] = __builtin_amdgcn_exp2f(fmaf(bp[r], LOG2EF, sacc[msub][r] * C1F));
            uint2 pk;
            pk.x = __builtin_amdgcn_perm(__float_as_uint(p[1]), __float_as_uint(p[0]), 0x07060302u);
            pk.y = __builtin_amdgcn_perm(__float_as_uint(p[3]), __float_as_uint(p[2]), 0x07060302u);
            *(uint2*)(Pb + msub * 2048 + pWr) = pk;
        }
        __syncthreads();   // P ready (also drains glds(ch+1) — mostly overlapped)

        // ---- PV phase: wave w owns msub {2w, 2w+1} ----
        const char* Vc = Vl + (cb << 12);
        __builtin_amdgcn_s_setprio(1);
#pragma unroll
        for (int kstep = 0; kstep < 2; ++kstep) {
            const int u = ((kstep * 4 + quad) ^ c7) << 4;
            const bf16x8 vf0 = *(const bf16x8*)(Vc + c * 128 + u);
            const bf16x8 vf1 = *(const bf16x8*)(Vc + (16 + c) * 128 + u);
#pragma unroll
            for (int mi = 0; mi < 2; ++mi) {
                const bf16x8 pf = *(const bf16x8*)(Pb + ((w * 2 + mi) * 16 + c) * 128 + u);
                oacc[0][mi] = __builtin_amdgcn_mfma_f32_16x16x32_bf16(vf0, pf, oacc[0][mi], 0, 0, 0);
                oacc[1][mi] = __builtin_amdgcn_mfma_f32_16x16x32_bf16(vf1, pf, oacc[1][mi], 0, 0, 0);
                dacc[mi]    = __builtin_amdgcn_mfma_f32_16x16x32_bf16(onesf, pf, dacc[mi], 0, 0, 0);
            }
        }
        __builtin_amdgcn_s_setprio(0);
    }

    // ---- epilogue: scale by 1/denominator, write O ----
    ushort_t* Ob = O + base;
#pragma unroll
    for (int mi = 0; mi < 2; ++mi) {
        const float inv = 1.0f / dacc[mi][0];
        const int m = m0 + (w * 2 + mi) * 16 + c;
#pragma unroll
        for (int ssub = 0; ssub < 2; ++ssub)
#pragma unroll
            for (int r = 0; r < 4; ++r)
                Ob[(size_t)(ssub * 16 + quad * 4 + r) * 1024 + m] = f2bf(oacc[ssub][mi][r] * inv);
    }
}

// ---------------------------------------------------------------------------
// Kernel 4: MFMA output projection + bias + residual (round-3 glds form).
// ---------------------------------------------------------------------------
__device__ __forceinline__ void oproj_stage(
    ushort_t* Sb, const ushort_t* __restrict__ A, const ushort_t* __restrict__ wo,
    int m0, int n0, int k0, int w, int lane)
{
    const int rsub = lane >> 3;
    const int u    = lane & 7;
    const int koct = u ^ rsub;
#pragma unroll
    for (int i = 0; i < 2; ++i) {
        const int rg  = w * 2 + i;
        const int row = rg * 8 + rsub;
        const int go  = k0 + koct * 8;
        ushort_t* db = Sb + rg * 512;
        glds16(&A [(size_t)(m0 + row) * 256 + go], db);
        glds16(&wo[(size_t)(n0 + row) * 256 + go], db + 4096);
    }
}

__device__ __forceinline__ void oproj_compute(
    const ushort_t* Sb, int w, int c, int quad, f32x4 acc[4])
{
#pragma unroll
    for (int ks = 0; ks < 2; ++ks) {
        const int kq = ks * 4 + quad;
        const int uo = (kq ^ (c & 7)) * 8;
        const bf16x8 bw = *(const bf16x8*)&Sb[4096 + (w * 16 + c) * 64 + uo];
#pragma unroll
        for (int msub = 0; msub < 4; ++msub) {
            const bf16x8 af = *(const bf16x8*)&Sb[(msub * 16 + c) * 64 + uo];
            acc[msub] = __builtin_amdgcn_mfma_f32_16x16x32_bf16(bw, af, acc[msub], 0, 0, 0);
        }
    }
}

__global__ __launch_bounds__(256, 4) void oproj_kernel(
    const ushort_t* __restrict__ A, const ushort_t* __restrict__ wo,
    const float* __restrict__ bo, const float* __restrict__ x,
    float* __restrict__ out)
{
    __shared__ __align__(16) ushort_t SA0[2][4096];
    __shared__ __align__(16) ushort_t SA1[2][4096];

    const int blk = blockIdx.x;
    const int m0  = (blk >> 2) << 6;
    const int n0  = (blk & 3) << 6;
    const int tid = threadIdx.x;
    const int w    = tid >> 6;
    const int lane = tid & 63;
    const int quad = lane >> 4;
    const int c    = lane & 15;

    f32x4 acc[4];
#pragma unroll
    for (int i = 0; i < 4; ++i) acc[i] = (f32x4){0.f, 0.f, 0.f, 0.f};

    oproj_stage(&SA0[0][0], A, wo, m0, n0, 0, w, lane);
    __syncthreads();
#pragma unroll
    for (int kc = 0; kc < 4; ++kc) {
        if (kc < 3) {
            if ((kc & 1) == 0)
                oproj_stage(&SA1[0][0], A, wo, m0, n0, (kc + 1) << 6, w, lane);
            else
                oproj_stage(&SA0[0][0], A, wo, m0, n0, (kc + 1) << 6, w, lane);
        }
        if ((kc & 1) == 0) oproj_compute(&SA0[0][0], w, c, quad, acc);
        else               oproj_compute(&SA1[0][0], w, c, quad, acc);
        __syncthreads();
    }

    const int n = n0 + w * 16 + quad * 4;
    const float4 bo4 = *(const float4*)&bo[n];
#pragma unroll
    for (int msub = 0; msub < 4; ++msub) {
        const size_t g = (size_t)(m0 + msub * 16 + c) * 256 + n;
        const float4 r = *(const float4*)&x[g];
        float4 t;
        t.x = acc[msub][0] + bo4.x + r.x;
        t.y = acc[msub][1] + bo4.y + r.y;
        t.z = acc[msub][2] + bo4.z + r.z;
        t.w = acc[msub][3] + bo4.w + r.w;
        *(float4*)&out[g] = t;
    }
}

// ---------------------------------------------------------------------------
extern "C" void kernel_launch(void* const* d_in, const int* in_sizes, int n_in,
                              void* d_out, int out_size, void* d_ws, size_t ws_size,
                              hipStream_t stream)
{
    (void)in_sizes; (void)n_in; (void)out_size; (void)ws_size;
    const float* x   = (const float*)d_in[0];
    const float* lng = (const float*)d_in[1];
    const float* lnb = (const float*)d_in[2];
    const float* wq  = (const float*)d_in[3];
    const float* bq  = (const float*)d_in[4];
    const float* wk  = (const float*)d_in[5];
    const float* bk  = (const float*)d_in[6];
    const float* wv  = (const float*)d_in[7];
    const float* bv  = (const float*)d_in[8];
    const float* wo  = (const float*)d_in[9];
    const float* bo  = (const float*)d_in[10];
    const float* rb  = (const float*)d_in[11];
    // d_in[12] (rel_idx) unused: index recomputed analytically in-kernel.

    ushort_t* ws = (ushort_t*)d_ws;
    ushort_t* Xbf = ws;                       // 4194304 elems each
    ushort_t* Qbf = ws + 1 * 4194304;         // QT token-major
    ushort_t* Kbf = ws + 2 * 4194304;         // KT token-major
    ushort_t* Vbf = ws + 3 * 4194304;         // V feature-major
    ushort_t* Obf = ws + 4 * 4194304;
    ushort_t* Wqb = ws + 5 * 4194304;
    ushort_t* Wkb = Wqb + 65536;
    ushort_t* Wvb = Wkb + 65536;
    ushort_t* Wob = Wvb + 65536;
    float* out = (float*)d_out;

    hipLaunchKernelGGL(prep_kernel,  dim3(768),  dim3(256), 0, stream,
                       x, lng, lnb, Xbf, wq, wk, wv, wo, Wqb, Wkb, Wvb, Wob);
    hipLaunchKernelGGL(qkv_kernel,   dim3(1024), dim3(256), 0, stream,
                       Xbf, Wqb, bq, Wkb, bk, Wvb, bv, Qbf, Kbf, Vbf);
    hipLaunchKernelGGL(attn_kernel,  dim3(1024), dim3(256), 0, stream, Qbf, Kbf, Vbf, rb, Obf);
    hipLaunchKernelGGL(oproj_kernel, dim3(1024), dim3(256), 0, stream, Obf, Wob, bo, x, out);
}

// Round 5
// 163.533 us; speedup vs baseline: 1.0324x; 1.0324x over previous
//
#include <hip/hip_runtime.h>
#include <cstdint>

#define PERB 262144   // C*H*H = N*D elements per batch

typedef __attribute__((ext_vector_type(8))) short bf16x8;
typedef __attribute__((ext_vector_type(4))) float f32x4;
typedef unsigned short ushort_t;

__device__ __forceinline__ uint16_t f2bf(float f) {
    uint32_t u = __float_as_uint(f);
    u += 0x7fff + ((u >> 16) & 1);   // RNE
    return (uint16_t)(u >> 16);
}

// async global->LDS, 16B per lane. LDS dest is wave-uniform base (+lane*16 by HW);
// global src is per-lane.
__device__ __forceinline__ void glds16(const void* g, void* l) {
    __builtin_amdgcn_global_load_lds(
        (const __attribute__((address_space(1))) void*)g,
        (__attribute__((address_space(3))) void*)l, 16, 0, 0);
}

// ---------------------------------------------------------------------------
// Kernel 0: fused prep.
//   blocks [0,256)   : convert the 4 weight matrices (256x256 fp32) to bf16
//   blocks [256,768) : LayerNorm over channel axis -> bf16 X
// ---------------------------------------------------------------------------
__global__ __launch_bounds__(256) void prep_kernel(
    const float* __restrict__ x, const float* __restrict__ gam,
    const float* __restrict__ bet, ushort_t* __restrict__ X,
    const float* __restrict__ wq, const float* __restrict__ wk,
    const float* __restrict__ wv, const float* __restrict__ wo,
    ushort_t* __restrict__ oq, ushort_t* __restrict__ ok,
    ushort_t* __restrict__ ov, ushort_t* __restrict__ oo)
{
    const int blk = blockIdx.x;
    const int tid = threadIdx.x;
    if (blk < 256) {
        const int which = blk >> 6;
        const int idx = ((blk & 63) * 256 + tid) * 4;
        const float* src = which == 0 ? wq : which == 1 ? wk : which == 2 ? wv : wo;
        ushort_t* dst    = which == 0 ? oq : which == 1 ? ok : which == 2 ? ov : oo;
        const float4 v = *(const float4*)&src[idx];
        uint2 p;
        p.x = (uint32_t)f2bf(v.x) | ((uint32_t)f2bf(v.y) << 16);
        p.y = (uint32_t)f2bf(v.z) | ((uint32_t)f2bf(v.w) << 16);
        *(uint2*)&dst[idx] = p;
        return;
    }
    const int lb  = blk - 256;            // 512 blocks
    const int b   = lb >> 5;
    const int sp0 = (lb & 31) << 5;
    const int spl = tid & 31;
    const int cg  = tid >> 5;
    const int c0  = cg << 5;
    const int sp  = sp0 + spl;
    const float* xb = x + (size_t)b * PERB + sp;

    float vals[32];
    float s = 0.f, sq = 0.f;
#pragma unroll
    for (int i = 0; i < 32; ++i) {
        float v = xb[(size_t)(c0 + i) * 1024];
        vals[i] = v; s += v; sq += v * v;
    }
    __shared__ float rs[8][32];
    __shared__ float rq[8][32];
    rs[cg][spl] = s; rq[cg][spl] = sq;
    __syncthreads();
    float ts = 0.f, tq = 0.f;
#pragma unroll
    for (int g = 0; g < 8; ++g) { ts += rs[g][spl]; tq += rq[g][spl]; }
    const float mean = ts * (1.f / 256.f);
    const float var  = tq * (1.f / 256.f) - mean * mean;
    const float rstd = rsqrtf(var + 1e-5f);

    ushort_t* Xb = X + (size_t)b * PERB + sp;
#pragma unroll
    for (int i = 0; i < 32; ++i) {
        const int cc = c0 + i;
        Xb[(size_t)cc * 1024] = f2bf((vals[i] - mean) * rstd * gam[cc] + bet[cc]);
    }
}

// ---------------------------------------------------------------------------
// Kernel 2: MFMA fused Q/K/V projection, round-12: m-tile 64 -> 128.
//  r3 structure (glds + XOR-swizzled src + dbuf) kept; per K-step now 48 MFMA
//  between barriers (af shared across 3 matrices), grid 1024 -> 512, so the
//  per-barrier glds drain is amortized over 2x compute and half as many
//  drains happen chip-wide. LDS 2x40KB -> 2 blocks/CU (512 blocks = exact fit).
// ---------------------------------------------------------------------------
__device__ __forceinline__ void qkv_stage(
    ushort_t* Sb, const ushort_t* __restrict__ X,
    const ushort_t* __restrict__ wq, const ushort_t* __restrict__ wk,
    const ushort_t* __restrict__ wv,
    int m0, int n0, int k0, int w, int lane)
{
    const int rsub = lane >> 3;          // 0..7  row-within-8-group
    const int u    = lane & 7;           // 16B unit within 128B row
    const int koct = u ^ rsub;           // pre-swizzled global k-octet
    const int go   = k0 + koct * 8;
    // X: 128 rows -> 16 groups, 4 per wave
#pragma unroll
    for (int i = 0; i < 4; ++i) {
        const int rg  = w * 4 + i;       // 0..15
        const int row = rg * 8 + rsub;   // row&7 == rsub
        glds16(&X[(size_t)(m0 + row) * 256 + go], Sb + rg * 512);
    }
    // W: 64 rows -> 8 groups, 2 per wave; panels at 8192 + mat*4096
#pragma unroll
    for (int i = 0; i < 2; ++i) {
        const int rg  = w * 2 + i;
        const int row = rg * 8 + rsub;
        ushort_t* db = Sb + 8192 + rg * 512;
        glds16(&wq[(size_t)(n0 + row) * 256 + go], db);
        glds16(&wk[(size_t)(n0 + row) * 256 + go], db + 4096);
        glds16(&wv[(size_t)(n0 + row) * 256 + go], db + 8192);
    }
}

__device__ __forceinline__ void qkv_compute(
    const ushort_t* Sb, int w, int c, int quad, f32x4 acc[3][8])
{
#pragma unroll
    for (int ks = 0; ks < 2; ++ks) {
        const int kq = ks * 4 + quad;
        const int uo = (kq ^ (c & 7)) * 8;
        bf16x8 bw[3];
#pragma unroll
        for (int o3 = 0; o3 < 3; ++o3)
            bw[o3] = *(const bf16x8*)&Sb[8192 + o3 * 4096 + (w * 16 + c) * 64 + uo];
#pragma unroll
        for (int msub = 0; msub < 8; ++msub) {
            const bf16x8 af = *(const bf16x8*)&Sb[(msub * 16 + c) * 64 + uo];
#pragma unroll
            for (int o3 = 0; o3 < 3; ++o3)
                acc[o3][msub] = __builtin_amdgcn_mfma_f32_16x16x32_bf16(
                    bw[o3], af, acc[o3][msub], 0, 0, 0);
        }
    }
}

__global__ __launch_bounds__(256) void qkv_kernel(
    const ushort_t* __restrict__ X,
    const ushort_t* __restrict__ wq, const float* __restrict__ bq,
    const ushort_t* __restrict__ wk, const float* __restrict__ bk,
    const ushort_t* __restrict__ wv, const float* __restrict__ bv,
    ushort_t* __restrict__ Q, ushort_t* __restrict__ K, ushort_t* __restrict__ V)
{
    // buffer = X[128x64] (16KB) + Wq/Wk/Wv[64x64] (8KB each) = 40KB, x2 dbuf
    __shared__ __align__(16) ushort_t SB0[20480];
    __shared__ __align__(16) ushort_t SB1[20480];

    const int blk = blockIdx.x;           // 512 blocks
    const int m0  = (blk >> 2) << 7;      // 128 m-tiles
    const int n0  = (blk & 3) << 6;
    const int tid = threadIdx.x;
    const int w    = tid >> 6;
    const int lane = tid & 63;
    const int quad = lane >> 4;
    const int c    = lane & 15;

    f32x4 acc[3][8];
#pragma unroll
    for (int o3 = 0; o3 < 3; ++o3)
#pragma unroll
        for (int i = 0; i < 8; ++i) acc[o3][i] = (f32x4){0.f, 0.f, 0.f, 0.f};

    qkv_stage(SB0, X, wq, wk, wv, m0, n0, 0, w, lane);
    __syncthreads();
#pragma unroll
    for (int kc = 0; kc < 4; ++kc) {
        if (kc < 3) {
            if ((kc & 1) == 0) qkv_stage(SB1, X, wq, wk, wv, m0, n0, (kc + 1) << 6, w, lane);
            else               qkv_stage(SB0, X, wq, wk, wv, m0, n0, (kc + 1) << 6, w, lane);
        }
        if ((kc & 1) == 0) qkv_compute(SB0, w, c, quad, acc);
        else               qkv_compute(SB1, w, c, quad, acc);
        __syncthreads();
    }

    const int n = n0 + w * 16 + quad * 4;
    const float4 bq4 = *(const float4*)&bq[n];
    const float4 bk4 = *(const float4*)&bk[n];
    const float4 bv4 = *(const float4*)&bv[n];
    ushort_t* outs[3] = {Q, K, V};
    const float4 bias[3] = {bq4, bk4, bv4};
#pragma unroll
    for (int msub = 0; msub < 8; ++msub) {
        const size_t m = (size_t)(m0 + msub * 16 + c);
#pragma unroll
        for (int o3 = 0; o3 < 3; ++o3) {
            const f32x4 a = acc[o3][msub];
            uint2 p;
            p.x = (uint32_t)f2bf(a[0] + bias[o3].x) | ((uint32_t)f2bf(a[1] + bias[o3].y) << 16);
            p.y = (uint32_t)f2bf(a[2] + bias[o3].z) | ((uint32_t)f2bf(a[3] + bias[o3].w) << 16);
            *(uint2*)&outs[o3][m * 256 + n] = p;
        }
    }
}

// ---------------------------------------------------------------------------
// Kernel 3: MFMA flash attention — round-0 configuration restored (measured
// 47.2us; reg-prefetch staging, m128 tile, 16 chunks, grid 1024). The glds
// experiment (r4) raised FETCH 37% (64B-stride 16B-use K reads) and could not
// hide latency in a 2-buffer loop (barrier drains the just-issued glds).
// ---------------------------------------------------------------------------
#define C1F 0.09016844005556022f   // 0.0625 * log2(e)
#define LOG2EF 1.4426950408889634f

__global__ __launch_bounds__(256, 4) void attn_kernel(
    const ushort_t* __restrict__ Q, const ushort_t* __restrict__ K,
    const ushort_t* __restrict__ V, const float* __restrict__ relb,
    ushort_t* __restrict__ O)
{
    // LDS map (bytes):
    //   [0, 16384)       P: 128 rows x 128B, 16B-unit swizzle; Q staging at start
    //   [16384, 20480)   K: granule (q=s>>3)*1024 + nn*16
    //   [20480, 28672)   V dbuf: buf*4096 + s*128, 16B-unit swizzle ^(s&7)
    __shared__ __align__(16) unsigned char smem[28672];
    char* Pb = (char*)smem;
    char* Kl = (char*)(smem + 16384);
    char* Vl = (char*)(smem + 20480);

    const int blk = blockIdx.x;
    const int bh  = blk & 127;
    const int mt  = blk >> 7;
    const int b   = bh >> 3;
    const int h   = bh & 7;
    const int m0  = mt << 7;
    const int tid = threadIdx.x;
    const int w    = tid >> 6;
    const int lane = tid & 63;
    const int quad = lane >> 4;
    const int c    = lane & 15;

    const size_t base = (size_t)b * PERB + (size_t)h * 32768;
    const ushort_t* Qg = Q + base;
    const ushort_t* Kg = K + base;
    const ushort_t* Vg = V + base;
    const float* rbh = relb + h * 3969;

    // ---- stage Q [32s x 128m] into Pb (granule layout), then read frags ----
    {
        const int mm = tid & 127;
        const int sg = tid >> 7;
        union { bf16x8 v; uint16_t u[8]; } g0, g1;
#pragma unroll
        for (int j = 0; j < 8; ++j)
            g0.u[j] = Qg[(size_t)(sg * 16 + j) * 1024 + m0 + mm];
#pragma unroll
        for (int j = 0; j < 8; ++j)
            g1.u[j] = Qg[(size_t)(sg * 16 + 8 + j) * 1024 + m0 + mm];
        *(bf16x8*)(Pb + (sg * 2 + 0) * 2048 + mm * 16) = g0.v;
        *(bf16x8*)(Pb + (sg * 2 + 1) * 2048 + mm * 16) = g1.v;
    }
    __syncthreads();
    bf16x8 qfrag[8];
#pragma unroll
    for (int msub = 0; msub < 8; ++msub)
        qfrag[msub] = *(const bf16x8*)(Pb + quad * 2048 + (msub * 16 + c) * 16);

    // per-msub bias m-offset: idx = noff(n) + moff(m)
    int moff[8];
#pragma unroll
    for (int msub = 0; msub < 8; ++msub) {
        const int m = m0 + msub * 16 + c;
        moff[msub] = 1984 - (m >> 5) * 63 - (m & 31);
    }

    // accumulators
    f32x4 oacc[2][2], dacc[2];
#pragma unroll
    for (int i = 0; i < 2; ++i) {
        dacc[i] = (f32x4){0.f, 0.f, 0.f, 0.f};
#pragma unroll
        for (int j = 0; j < 2; ++j) oacc[i][j] = (f32x4){0.f, 0.f, 0.f, 0.f};
    }
    bf16x8 onesf;
#pragma unroll
    for (int j = 0; j < 8; ++j) onesf[j] = (short)0x3F80;

    // staging thread coords + hoisted LDS addresses
    const int knn = tid & 63, ksg = tid >> 6;   // K: 8 s-values for column knn
    const int vs  = tid >> 3, vng = tid & 7;    // V: unit16 vng of row vs
    const int kWr = ksg * 1024 + knn * 16;
    const int vWr = vs * 128 + ((vng ^ (vs & 7)) << 4);
    const int kRd = quad * 1024 + (w * 16 + c) * 16;
    const int pWr = c * 128 + (((2 * w + (quad >> 1)) ^ (c & 7)) << 4) + ((quad & 1) << 3);
    const int c7  = c & 7;

    // prologue: prefetch chunk 0
    uint32_t kpre[8]; bf16x8 vpre;
#pragma unroll
    for (int j = 0; j < 8; ++j) kpre[j] = Kg[(size_t)(ksg * 8 + j) * 1024 + knn];
    vpre = *(const bf16x8*)&Vg[(size_t)vs * 1024 + vng * 8];

    for (int ch = 0; ch < 16; ++ch) {
        const int n0c = ch << 6;
        const int cb  = ch & 1;

        // ---- write prefetched K/V to LDS ----
        {
            uint4 kp;
            kp.x = kpre[0] | (kpre[1] << 16);
            kp.y = kpre[2] | (kpre[3] << 16);
            kp.z = kpre[4] | (kpre[5] << 16);
            kp.w = kpre[6] | (kpre[7] << 16);
            *(uint4*)(Kl + kWr) = kp;
            *(bf16x8*)(Vl + cb * 4096 + vWr) = vpre;
        }
        __syncthreads();   // staging visible; prev PV done for all waves

        // ---- prefetch next chunk into regs (overlaps S phase) ----
        {
            const int n0n = ((ch + 1) & 15) << 6;
#pragma unroll
            for (int j = 0; j < 8; ++j)
                kpre[j] = Kg[(size_t)(ksg * 8 + j) * 1024 + n0n + knn];
            vpre = *(const bf16x8*)&Vg[(size_t)vs * 1024 + n0n + vng * 8];
        }

        // ---- S phase ----
        const bf16x8 kf = *(const bf16x8*)(Kl + kRd);
        f32x4 sacc[8];
#pragma unroll
        for (int msub = 0; msub < 8; ++msub) {
            const f32x4 z = {0.f, 0.f, 0.f, 0.f};
            sacc[msub] = __builtin_amdgcn_mfma_f32_16x16x32_bf16(kf, qfrag[msub], z, 0, 0, 0);
        }

        // ---- bias (global, L1/L2-hit) + exp2 + trunc-pack + P write ----
        const int nbase = n0c + w * 16 + quad * 4;
        const int nidx0 = (nbase >> 5) * 63 + (nbase & 31);  // 4 consecutive ints follow
#pragma unroll
        for (int msub = 0; msub < 8; ++msub) {
            const float* bp = rbh + nidx0 + moff[msub];
            float p[4];
#pragma unroll
            for (int r = 0; r < 4; ++r)
                p[r] = __builtin_amdgcn_exp2f(fmaf(bp[r], LOG2EF, sacc[msub][r] * C1F));
            uint2 pk;
            pk.x = __builtin_amdgcn_perm(__float_as_uint(p[1]), __float_as_uint(p[0]), 0x07060302u);
            pk.y = __builtin_amdgcn_perm(__float_as_uint(p[3]), __float_as_uint(p[2]), 0x07060302u);
            *(uint2*)(Pb + msub * 2048 + pWr) = pk;
        }
        __syncthreads();   // P (and V) ready for PV

        // ---- PV phase: wave w owns msub {2w, 2w+1} ----
#pragma unroll
        for (int kstep = 0; kstep < 2; ++kstep) {
            const int u = ((kstep * 4 + quad) ^ c7) << 4;
            const bf16x8 vf0 = *(const bf16x8*)(Vl + cb * 4096 + c * 128 + u);
            const bf16x8 vf1 = *(const bf16x8*)(Vl + cb * 4096 + (16 + c) * 128 + u);
#pragma unroll
            for (int mi = 0; mi < 2; ++mi) {
                const bf16x8 pf = *(const bf16x8*)(Pb + ((w * 2 + mi) * 16 + c) * 128 + u);
                oacc[0][mi] = __builtin_amdgcn_mfma_f32_16x16x32_bf16(vf0, pf, oacc[0][mi], 0, 0, 0);
                oacc[1][mi] = __builtin_amdgcn_mfma_f32_16x16x32_bf16(vf1, pf, oacc[1][mi], 0, 0, 0);
                dacc[mi]    = __builtin_amdgcn_mfma_f32_16x16x32_bf16(onesf, pf, dacc[mi], 0, 0, 0);
            }
        }
    }

    // ---- epilogue: scale by 1/denominator, write O ----
    ushort_t* Ob = O + base;
#pragma unroll
    for (int mi = 0; mi < 2; ++mi) {
        const float inv = 1.0f / dacc[mi][0];
        const int m = m0 + (w * 2 + mi) * 16 + c;
#pragma unroll
        for (int ssub = 0; ssub < 2; ++ssub)
#pragma unroll
            for (int r = 0; r < 4; ++r)
                Ob[(size_t)(ssub * 16 + quad * 4 + r) * 1024 + m] = f2bf(oacc[ssub][mi][r] * inv);
    }
}

// ---------------------------------------------------------------------------
// Kernel 4: MFMA output projection + bias + residual, m-tile 128 (round-12).
// ---------------------------------------------------------------------------
__device__ __forceinline__ void oproj_stage(
    ushort_t* Sb, const ushort_t* __restrict__ A, const ushort_t* __restrict__ wo,
    int m0, int n0, int k0, int w, int lane)
{
    const int rsub = lane >> 3;
    const int u    = lane & 7;
    const int koct = u ^ rsub;
    const int go   = k0 + koct * 8;
#pragma unroll
    for (int i = 0; i < 4; ++i) {
        const int rg  = w * 4 + i;
        const int row = rg * 8 + rsub;
        glds16(&A[(size_t)(m0 + row) * 256 + go], Sb + rg * 512);
    }
#pragma unroll
    for (int i = 0; i < 2; ++i) {
        const int rg  = w * 2 + i;
        const int row = rg * 8 + rsub;
        glds16(&wo[(size_t)(n0 + row) * 256 + go], Sb + 8192 + rg * 512);
    }
}

__device__ __forceinline__ void oproj_compute(
    const ushort_t* Sb, int w, int c, int quad, f32x4 acc[8])
{
#pragma unroll
    for (int ks = 0; ks < 2; ++ks) {
        const int kq = ks * 4 + quad;
        const int uo = (kq ^ (c & 7)) * 8;
        const bf16x8 bw = *(const bf16x8*)&Sb[8192 + (w * 16 + c) * 64 + uo];
#pragma unroll
        for (int msub = 0; msub < 8; ++msub) {
            const bf16x8 af = *(const bf16x8*)&Sb[(msub * 16 + c) * 64 + uo];
            acc[msub] = __builtin_amdgcn_mfma_f32_16x16x32_bf16(bw, af, acc[msub], 0, 0, 0);
        }
    }
}

__global__ __launch_bounds__(256) void oproj_kernel(
    const ushort_t* __restrict__ A, const ushort_t* __restrict__ wo,
    const float* __restrict__ bo, const float* __restrict__ x,
    float* __restrict__ out)
{
    // buffer = A[128x64] (16KB) + wo[64x64] (8KB) = 24KB, x2 dbuf -> 3 blk/CU
    __shared__ __align__(16) ushort_t SA0[12288];
    __shared__ __align__(16) ushort_t SA1[12288];

    const int blk = blockIdx.x;           // 512 blocks
    const int m0  = (blk >> 2) << 7;
    const int n0  = (blk & 3) << 6;
    const int tid = threadIdx.x;
    const int w    = tid >> 6;
    const int lane = tid & 63;
    const int quad = lane >> 4;
    const int c    = lane & 15;

    f32x4 acc[8];
#pragma unroll
    for (int i = 0; i < 8; ++i) acc[i] = (f32x4){0.f, 0.f, 0.f, 0.f};

    oproj_stage(SA0, A, wo, m0, n0, 0, w, lane);
    __syncthreads();
#pragma unroll
    for (int kc = 0; kc < 4; ++kc) {
        if (kc < 3) {
            if ((kc & 1) == 0) oproj_stage(SA1, A, wo, m0, n0, (kc + 1) << 6, w, lane);
            else               oproj_stage(SA0, A, wo, m0, n0, (kc + 1) << 6, w, lane);
        }
        if ((kc & 1) == 0) oproj_compute(SA0, w, c, quad, acc);
        else               oproj_compute(SA1, w, c, quad, acc);
        __syncthreads();
    }

    const int n = n0 + w * 16 + quad * 4;
    const float4 bo4 = *(const float4*)&bo[n];
#pragma unroll
    for (int msub = 0; msub < 8; ++msub) {
        const size_t g = (size_t)(m0 + msub * 16 + c) * 256 + n;
        const float4 r = *(const float4*)&x[g];
        float4 t;
        t.x = acc[msub][0] + bo4.x + r.x;
        t.y = acc[msub][1] + bo4.y + r.y;
        t.z = acc[msub][2] + bo4.z + r.z;
        t.w = acc[msub][3] + bo4.w + r.w;
        *(float4*)&out[g] = t;
    }
}

// ---------------------------------------------------------------------------
extern "C" void kernel_launch(void* const* d_in, const int* in_sizes, int n_in,
                              void* d_out, int out_size, void* d_ws, size_t ws_size,
                              hipStream_t stream)
{
    (void)in_sizes; (void)n_in; (void)out_size; (void)ws_size;
    const float* x   = (const float*)d_in[0];
    const float* lng = (const float*)d_in[1];
    const float* lnb = (const float*)d_in[2];
    const float* wq  = (const float*)d_in[3];
    const float* bq  = (const float*)d_in[4];
    const float* wk  = (const float*)d_in[5];
    const float* bk  = (const float*)d_in[6];
    const float* wv  = (const float*)d_in[7];
    const float* bv  = (const float*)d_in[8];
    const float* wo  = (const float*)d_in[9];
    const float* bo  = (const float*)d_in[10];
    const float* rb  = (const float*)d_in[11];
    // d_in[12] (rel_idx) unused: index recomputed analytically in-kernel.

    ushort_t* ws = (ushort_t*)d_ws;
    ushort_t* Xbf = ws;                       // 4194304 elems each
    ushort_t* Qbf = ws + 1 * 4194304;
    ushort_t* Kbf = ws + 2 * 4194304;
    ushort_t* Vbf = ws + 3 * 4194304;
    ushort_t* Obf = ws + 4 * 4194304;
    ushort_t* Wqb = ws + 5 * 4194304;
    ushort_t* Wkb = Wqb + 65536;
    ushort_t* Wvb = Wkb + 65536;
    ushort_t* Wob = Wvb + 65536;
    float* out = (float*)d_out;

    hipLaunchKernelGGL(prep_kernel,  dim3(768),  dim3(256), 0, stream,
                       x, lng, lnb, Xbf, wq, wk, wv, wo, Wqb, Wkb, Wvb, Wob);
    hipLaunchKernelGGL(qkv_kernel,   dim3(512),  dim3(256), 0, stream,
                       Xbf, Wqb, bq, Wkb, bk, Wvb, bv, Qbf, Kbf, Vbf);
    hipLaunchKernelGGL(attn_kernel,  dim3(1024), dim3(256), 0, stream, Qbf, Kbf, Vbf, rb, Obf);
    hipLaunchKernelGGL(oproj_kernel, dim3(512),  dim3(256), 0, stream, Obf, Wob, bo, x, out);
}